// Round 9
// baseline (165.305 us; speedup 1.0000x reference)
//
#include <hip/hip_runtime.h>
#include <math.h>

#define RS2f 0.70710678118654752f

typedef __attribute__((ext_vector_type(8))) short bf16x8;
typedef __attribute__((ext_vector_type(4))) float f32x4;

__device__ __forceinline__ unsigned short f2bf(float f) {
    unsigned u = __float_as_uint(f);
    unsigned r = (u + 0x7fffu + ((u >> 16) & 1u)) >> 16;   // RNE
    return (unsigned short)r;
}
__device__ __forceinline__ float bf2f(unsigned short h) {
    return __uint_as_float(((unsigned)h) << 16);
}

// ==================================================================
// Fused convert: x (1024x2048) and W (512x2048) fp32 -> bf16 hi/lo
// concat along K (row stride 4096 = [hi | lo]).
// ==================================================================
__global__ __launch_bounds__(256) void split_all(const float* __restrict__ x,
                                                 const float* __restrict__ W,
                                                 unsigned short* __restrict__ xc,
                                                 unsigned short* __restrict__ wc) {
    int idx = blockIdx.x * 256 + threadIdx.x;      // 786432 total
    const float* src; unsigned short* dst;
    if (idx < 524288) { src = x; dst = xc; }
    else              { idx -= 524288; src = W; dst = wc; }
    int m = idx >> 9;
    int c4 = (idx & 511) << 2;
    const float4 v = *(const float4*)&src[m * 2048 + c4];
    ushort4 hi, lo;
    hi.x = f2bf(v.x); lo.x = f2bf(v.x - bf2f(hi.x));
    hi.y = f2bf(v.y); lo.y = f2bf(v.y - bf2f(hi.y));
    hi.z = f2bf(v.z); lo.z = f2bf(v.z - bf2f(hi.z));
    hi.w = f2bf(v.w); lo.w = f2bf(v.w - bf2f(hi.w));
    *(ushort4*)&dst[m * 4096 + c4] = hi;
    *(ushort4*)&dst[m * 4096 + 2048 + c4] = lo;
}

// ==================================================================
// LDS-free, barrier-free MFMA GEMM partials.
// Each WAVE owns a (16*AM x 64) output tile and streams its K-chunk
// with direct global->fragment dwordx4 loads (fragment layout
// [row=lane&15][k=quad*8+j] is K-contiguous => no staging needed).
// NSTEPS k-steps of 32; SK = 128/NSTEPS slabs. Double-buffered
// register prefetch; zero __syncthreads.
// ==================================================================
template<int AM, int NSTEPS>
__global__ __launch_bounds__(256) void gemm_tile(const unsigned short* __restrict__ A,  // 1024x4096
                                                 const unsigned short* __restrict__ B,  // 512x4096
                                                 float* __restrict__ P) {
    const int tid = threadIdx.x, lane = tid & 63, wv = tid >> 6;
    const int tpz = (1024 / (16 * AM)) * 8 / 4;    // blocks per z
    const int bz = blockIdx.x / tpz;
    const int bt = blockIdx.x % tpz;
    const int tile = bt * 4 + wv;
    const int mt = tile >> 3, nt = tile & 7;
    const int m0 = mt * 16 * AM, n0 = nt * 64;
    const int kb = bz * NSTEPS * 32;
    const int quad = lane >> 4, mrow = lane & 15;
    const unsigned short* Ab = A + (size_t)(m0 + mrow) * 4096 + kb + quad * 8;
    const unsigned short* Bb = B + (size_t)(n0 + mrow) * 4096 + kb + quad * 8;

    f32x4 acc[AM][4];
    #pragma unroll
    for (int i = 0; i < AM; ++i)
        #pragma unroll
        for (int j = 0; j < 4; ++j) acc[i][j] = (f32x4){0.f, 0.f, 0.f, 0.f};

    bf16x8 af[2][AM], bf[2][4];
    #pragma unroll
    for (int i = 0; i < AM; ++i) af[0][i] = *(const bf16x8*)(Ab + (size_t)i * 16 * 4096);
    #pragma unroll
    for (int j = 0; j < 4; ++j)  bf[0][j] = *(const bf16x8*)(Bb + (size_t)j * 16 * 4096);

    #pragma unroll
    for (int s = 0; s < NSTEPS; ++s) {
        const int cur = s & 1, nxt = cur ^ 1;
        if (s + 1 < NSTEPS) {
            #pragma unroll
            for (int i = 0; i < AM; ++i)
                af[nxt][i] = *(const bf16x8*)(Ab + (s + 1) * 32 + (size_t)i * 16 * 4096);
            #pragma unroll
            for (int j = 0; j < 4; ++j)
                bf[nxt][j] = *(const bf16x8*)(Bb + (s + 1) * 32 + (size_t)j * 16 * 4096);
        }
        #pragma unroll
        for (int i = 0; i < AM; ++i)
            #pragma unroll
            for (int j = 0; j < 4; ++j)
                acc[i][j] = __builtin_amdgcn_mfma_f32_16x16x32_bf16(af[cur][i], bf[cur][j],
                                                                    acc[i][j], 0, 0, 0);
    }

    float* Pz = P + (size_t)bz * 524288;
    #pragma unroll
    for (int i = 0; i < AM; ++i)
        #pragma unroll
        for (int r = 0; r < 4; ++r) {
            const int m = m0 + 16 * i + quad * 4 + r;
            #pragma unroll
            for (int j = 0; j < 4; ++j)
                Pz[m * 512 + n0 + 16 * j + mrow] = acc[i][j][r];
        }
}

// ==================================================================
// reduce partials + bias -> com (written over slab 0)
// ==================================================================
__global__ __launch_bounds__(256) void reduce_kernel(float* __restrict__ P,
                                                     const float* __restrict__ bias,
                                                     int SK) {
    int i = blockIdx.x * 256 + threadIdx.x;        // 512K total
    float s = bias[i & 511];
    for (int z = 0; z < SK; ++z) s += P[z * 524288 + i];
    P[i] = s;
}

// ==================================================================
// Fallback fp32 GEMM (only if ws too small for bf16 buffers)
// ==================================================================
__global__ __launch_bounds__(256) void gemm_f32(const float* __restrict__ A,
                                                const float* __restrict__ W,
                                                float* __restrict__ P) {
    __shared__ float Asf[32][128];
    __shared__ float Bsf[32][128];
    const int tid = threadIdx.x;
    const int m0 = blockIdx.x * 128;
    const int n0 = blockIdx.y * 128;
    const int kchunk = 2048 / gridDim.z;
    const int kbase = blockIdx.z * kchunk;
    const int tm = tid >> 4, tn = tid & 15;
    const int srow = tid >> 1;
    const int scol = (tid & 1) * 16;
    float acc[8][8] = {};
    for (int k0 = kbase; k0 < kbase + kchunk; k0 += 32) {
        float4 a[4], w[4];
        const float4* Ap = (const float4*)&A[(m0 + srow) * 2048 + k0 + scol];
        const float4* Wp = (const float4*)&W[(n0 + srow) * 2048 + k0 + scol];
        #pragma unroll
        for (int q = 0; q < 4; ++q) { a[q] = Ap[q]; w[q] = Wp[q]; }
        __syncthreads();
        #pragma unroll
        for (int q = 0; q < 4; ++q) {
            Asf[scol + 4*q + 0][srow] = a[q].x; Asf[scol + 4*q + 1][srow] = a[q].y;
            Asf[scol + 4*q + 2][srow] = a[q].z; Asf[scol + 4*q + 3][srow] = a[q].w;
            Bsf[scol + 4*q + 0][srow] = w[q].x; Bsf[scol + 4*q + 1][srow] = w[q].y;
            Bsf[scol + 4*q + 2][srow] = w[q].z; Bsf[scol + 4*q + 3][srow] = w[q].w;
        }
        __syncthreads();
        #pragma unroll
        for (int kk = 0; kk < 32; ++kk) {
            float4 af0 = *(const float4*)&Asf[kk][tm * 8];
            float4 af1 = *(const float4*)&Asf[kk][tm * 8 + 4];
            float4 bf0 = *(const float4*)&Bsf[kk][tn * 8];
            float4 bf1 = *(const float4*)&Bsf[kk][tn * 8 + 4];
            float av[8] = {af0.x,af0.y,af0.z,af0.w,af1.x,af1.y,af1.z,af1.w};
            float bv[8] = {bf0.x,bf0.y,bf0.z,bf0.w,bf1.x,bf1.y,bf1.z,bf1.w};
            #pragma unroll
            for (int r = 0; r < 8; ++r)
                #pragma unroll
                for (int c = 0; c < 8; ++c)
                    acc[r][c] += av[r] * bv[c];
        }
    }
    float* Pz = P + (size_t)blockIdx.z * 524288;
    #pragma unroll
    for (int r = 0; r < 8; ++r) {
        float4 lo = make_float4(acc[r][0], acc[r][1], acc[r][2], acc[r][3]);
        float4 hi = make_float4(acc[r][4], acc[r][5], acc[r][6], acc[r][7]);
        float* dst = &Pz[(m0 + tm*8 + r) * 512 + n0 + tn*8];
        *(float4*)dst = lo;
        *(float4*)(dst + 4) = hi;
    }
}

// ==================================================================
// Kernel 3: 12-qubit circuit — EXACT R5/R8 structure (77 us measured;
// half-pass and cmt-hoist variants both regressed -- do not touch).
//   idx = (w1<<11) | (lane<<5) | (w0<<4) | e,  waveId = (w1<<1)|w0
//   V-wires: wire0 -> vm=2, wire7 -> vm=1
//   L-wires: wires1..6 -> lane bits 5..0
//   E-wires: wires8..11 -> e bits 3..0
// ==================================================================
struct CMat { float m00r,m00i,m01r,m01i,m10r,m10i,m11r,m11i; };

__device__ __forceinline__ CMat mk_rot(const float* __restrict__ qp, int l, int w) {
    const float* g = qp + (l * 12 + w) * 3;
    float phi = g[0], th = g[1], om = g[2];
    float st, ct, sa, ca, sb, cb;
    sincosf(0.5f * th, &st, &ct);
    sincosf(0.5f * (phi + om), &sa, &ca);
    sincosf(0.5f * (phi - om), &sb, &cb);
    CMat M;
    M.m00r =  ct * ca; M.m00i = -ct * sa;
    M.m01r = -st * cb; M.m01i = -st * sb;
    M.m10r =  st * cb; M.m10i = -st * sb;
    M.m11r =  ct * ca; M.m11i =  ct * sa;
    return M;
}

template<int W> struct WI {
    static constexpr int kind = (W == 0 || W == 7) ? 2 : ((W >= 1 && W <= 6) ? 1 : 0);
    static constexpr int eb   = (W >= 8) ? (11 - W) : 0;
    static constexpr int lm   = (W >= 1 && W <= 6) ? (1 << (6 - W)) : 0;
    static constexpr int vm   = (W == 0) ? 2 : ((W == 7) ? 1 : 0);
};

__device__ __forceinline__ void exch_put(float* xbuf, int slot,
                                         const float vr[16], const float vi[16]) {
    __syncthreads();
    float4* p = (float4*)xbuf;
    #pragma unroll
    for (int j = 0; j < 8; ++j)
        p[(j << 8) + slot] = make_float4(vr[2*j], vi[2*j], vr[2*j+1], vi[2*j+1]);
    __syncthreads();
}

__device__ __forceinline__ void shfl_perm(float vr[16], float vi[16], int src) {
    #pragma unroll
    for (int e = 0; e < 16; ++e) {
        vr[e] = __shfl(vr[e], src, 64);
        vi[e] = __shfl(vi[e], src, 64);
    }
}

template<int EB>
__device__ __forceinline__ void rot_local(float vr[16], float vi[16], const CMat& M) {
    #pragma unroll
    for (int e = 0; e < 16; ++e) if (!(e & (1 << EB))) {
        const int e1 = e | (1 << EB);
        float x0r = vr[e],  x0i = vi[e];
        float x1r = vr[e1], x1i = vi[e1];
        vr[e]  = M.m00r*x0r - M.m00i*x0i + M.m01r*x1r - M.m01i*x1i;
        vi[e]  = M.m00r*x0i + M.m00i*x0r + M.m01r*x1i + M.m01i*x1r;
        vr[e1] = M.m10r*x0r - M.m10i*x0i + M.m11r*x1r - M.m11i*x1i;
        vi[e1] = M.m10r*x0i + M.m10i*x0r + M.m11r*x1i + M.m11i*x1r;
    }
}

template<int LM>
__device__ __forceinline__ void rot_lane(float vr[16], float vi[16], int lane, const CMat& M) {
    const bool hi = lane & LM;
    const float Ar = hi ? M.m11r : M.m00r, Ai = hi ? M.m11i : M.m00i;
    const float Br = hi ? M.m10r : M.m01r, Bi = hi ? M.m10i : M.m01i;
    #pragma unroll
    for (int e = 0; e < 16; ++e) {
        float pr = __shfl_xor(vr[e], LM, 64);
        float pi = __shfl_xor(vi[e], LM, 64);
        float orr = vr[e], oi = vi[e];
        vr[e] = Ar*orr - Ai*oi + Br*pr - Bi*pi;
        vi[e] = Ar*oi + Ai*orr + Br*pi + Bi*pr;
    }
}

template<int VM>
__device__ __forceinline__ void rot_wave(float vr[16], float vi[16], float* xbuf,
                                         int waveId, int lane, const CMat& M) {
    exch_put(xbuf, (waveId << 6) + lane, vr, vi);
    const float4* p = (const float4*)xbuf;
    const int ps = ((waveId ^ VM) << 6) + lane;
    const bool hi = waveId & VM;
    const float Ar = hi ? M.m11r : M.m00r, Ai = hi ? M.m11i : M.m00i;
    const float Br = hi ? M.m10r : M.m01r, Bi = hi ? M.m10i : M.m01i;
    #pragma unroll
    for (int j = 0; j < 8; ++j) {
        float4 q = p[(j << 8) + ps];
        const int e0 = 2*j, e1 = 2*j + 1;
        float r0 = vr[e0], i0 = vi[e0], r1 = vr[e1], i1 = vi[e1];
        vr[e0] = Ar*r0 - Ai*i0 + Br*q.x - Bi*q.y;
        vi[e0] = Ar*i0 + Ai*r0 + Br*q.y + Bi*q.x;
        vr[e1] = Ar*r1 - Ai*i1 + Br*q.z - Bi*q.w;
        vi[e1] = Ar*i1 + Ai*r1 + Br*q.w + Bi*q.z;
    }
}

template<int W>
__device__ __forceinline__ void rot_wire(float vr[16], float vi[16], float* xbuf,
                                         int waveId, int lane, const CMat& M) {
    if constexpr (WI<W>::kind == 0)      rot_local<WI<W>::eb>(vr, vi, M);
    else if constexpr (WI<W>::kind == 1) rot_lane<WI<W>::lm>(vr, vi, lane, M);
    else                                 rot_wave<WI<W>::vm>(vr, vi, xbuf, waveId, lane, M);
}

template<int C, int T>
__device__ __forceinline__ void cnot(float vr[16], float vi[16], float* xbuf,
                                     int waveId, int lane) {
    constexpr int ck = WI<C>::kind, tk = WI<T>::kind;
    if constexpr (ck == 0 && tk == 0) {
        constexpr int cb = 1 << WI<C>::eb, tb = 1 << WI<T>::eb;
        #pragma unroll
        for (int e = 0; e < 16; ++e) if ((e & cb) && !(e & tb)) {
            const int e1 = e | tb;
            float t = vr[e]; vr[e] = vr[e1]; vr[e1] = t;
            t = vi[e]; vi[e] = vi[e1]; vi[e1] = t;
        }
    } else if constexpr (ck == 0 && tk == 1) {
        constexpr int cb = 1 << WI<C>::eb, tm = WI<T>::lm;
        #pragma unroll
        for (int e = 0; e < 16; ++e) if (e & cb) {
            vr[e] = __shfl_xor(vr[e], tm, 64);
            vi[e] = __shfl_xor(vi[e], tm, 64);
        }
    } else if constexpr (ck == 0 && tk == 2) {
        constexpr int cb = 1 << WI<C>::eb, vm = WI<T>::vm;
        exch_put(xbuf, (waveId << 6) + lane, vr, vi);
        const float4* p = (const float4*)xbuf;
        const int ps = ((waveId ^ vm) << 6) + lane;
        #pragma unroll
        for (int j = 0; j < 8; ++j) {
            if ((((2*j) & cb) != 0) || (((2*j+1) & cb) != 0)) {
                float4 q = p[(j << 8) + ps];
                if (((2*j) & cb) != 0)   { vr[2*j]   = q.x; vi[2*j]   = q.y; }
                if (((2*j+1) & cb) != 0) { vr[2*j+1] = q.z; vi[2*j+1] = q.w; }
            }
        }
    } else if constexpr (ck == 1 && tk == 0) {
        constexpr int cm = WI<C>::lm, tb = 1 << WI<T>::eb;
        const bool cc = lane & cm;
        #pragma unroll
        for (int e = 0; e < 16; ++e) if (!(e & tb)) {
            const int e1 = e | tb;
            float a = vr[e], bb = vr[e1];
            vr[e] = cc ? bb : a; vr[e1] = cc ? a : bb;
            a = vi[e]; bb = vi[e1];
            vi[e] = cc ? bb : a; vi[e1] = cc ? a : bb;
        }
    } else if constexpr (ck == 1 && tk == 1) {
        constexpr int cm = WI<C>::lm, tm = WI<T>::lm;
        const int src = (lane & cm) ? (lane ^ tm) : lane;
        shfl_perm(vr, vi, src);
    } else if constexpr (ck == 1 && tk == 2) {
        constexpr int cm = WI<C>::lm, vm = WI<T>::vm;
        exch_put(xbuf, (waveId << 6) + lane, vr, vi);
        const float4* p = (const float4*)xbuf;
        const int ps = ((waveId ^ vm) << 6) + lane;
        const bool take = lane & cm;
        #pragma unroll
        for (int j = 0; j < 8; ++j) {
            float4 q = p[(j << 8) + ps];
            vr[2*j]   = take ? q.x : vr[2*j];   vi[2*j]   = take ? q.y : vi[2*j];
            vr[2*j+1] = take ? q.z : vr[2*j+1]; vi[2*j+1] = take ? q.w : vi[2*j+1];
        }
    } else if constexpr (ck == 2 && tk == 0) {
        constexpr int vm = WI<C>::vm, tb = 1 << WI<T>::eb;
        if (waveId & vm) {
            #pragma unroll
            for (int e = 0; e < 16; ++e) if (!(e & tb)) {
                const int e1 = e | tb;
                float t = vr[e]; vr[e] = vr[e1]; vr[e1] = t;
                t = vi[e]; vi[e] = vi[e1]; vi[e1] = t;
            }
        }
    } else {
        constexpr int vm = WI<C>::vm, tm = WI<T>::lm;
        if (waveId & vm) {
            #pragma unroll
            for (int e = 0; e < 16; ++e) {
                vr[e] = __shfl_xor(vr[e], tm, 64);
                vi[e] = __shfl_xor(vi[e], tm, 64);
            }
        }
    }
}

template<int W>
__device__ __forceinline__ void h_wire(float vr[16], float vi[16], float* xbuf,
                                       int waveId, int lane) {
    if constexpr (WI<W>::kind == 0) {
        constexpr int tb = 1 << WI<W>::eb;
        #pragma unroll
        for (int e = 0; e < 16; ++e) if (!(e & tb)) {
            const int e1 = e | tb;
            float x0 = vr[e], x1 = vr[e1];
            vr[e] = (x0 + x1) * RS2f; vr[e1] = (x0 - x1) * RS2f;
            x0 = vi[e]; x1 = vi[e1];
            vi[e] = (x0 + x1) * RS2f; vi[e1] = (x0 - x1) * RS2f;
        }
    } else if constexpr (WI<W>::kind == 1) {
        constexpr int m = WI<W>::lm;
        const float sgn = (lane & m) ? -RS2f : RS2f;
        #pragma unroll
        for (int e = 0; e < 16; ++e) {
            float pr = __shfl_xor(vr[e], m, 64);
            float pi = __shfl_xor(vi[e], m, 64);
            vr[e] = pr * RS2f + vr[e] * sgn;
            vi[e] = pi * RS2f + vi[e] * sgn;
        }
    } else {
        constexpr int vm = WI<W>::vm;
        exch_put(xbuf, (waveId << 6) + lane, vr, vi);
        const float4* p = (const float4*)xbuf;
        const int ps = ((waveId ^ vm) << 6) + lane;
        const float sgn = (waveId & vm) ? -RS2f : RS2f;
        #pragma unroll
        for (int j = 0; j < 8; ++j) {
            float4 q = p[(j << 8) + ps];
            vr[2*j]   = q.x * RS2f + vr[2*j]   * sgn;
            vi[2*j]   = q.y * RS2f + vi[2*j]   * sgn;
            vr[2*j+1] = q.z * RS2f + vr[2*j+1] * sgn;
            vi[2*j+1] = q.w * RS2f + vi[2*j+1] * sgn;
        }
    }
}

__global__ __launch_bounds__(256) void circuit_kernel(const float* __restrict__ com,
                                                      const float* __restrict__ xf,
                                                      const float* __restrict__ qp,
                                                      float* __restrict__ out) {
    __shared__ float xbuf[8192];         // 32 KB exchange buffer
    __shared__ float ang[2048];          // 8 KB: com row, later xf row
    const int tid = threadIdx.x;
    const int lane = tid & 63;
    const int waveId = tid >> 6;
    const int b = blockIdx.x;

    if (tid < 128) ((float4*)ang)[tid] = ((const float4*)(com + b * 512))[tid];
    __syncthreads();

    float vr[16], vi[16];
    #pragma unroll
    for (int e = 0; e < 16; ++e) { vr[e] = 0.0f; vi[e] = 0.0f; }

    // FRQI-1 closed form: amp nonzero where wires10,11 = 0 -> e in {0,4,8,12}
    const float K9 = 0.044194173824159216f;   // 2^-4.5
    #pragma unroll
    for (int m = 0; m < 4; ++m) {
        int j = (lane << 3) | ((waveId & 1) << 2) | m;
        int rj = (int)(__brev((unsigned)j) >> 23);
        float s, c;
        sincosf(0.5f * ang[rj], &s, &c);
        vr[m << 2] = K9 * ((waveId & 2) ? s : c);
    }

    #pragma unroll 1
    for (int l = 0; l < 2; ++l) {
        { CMat M = mk_rot(qp, l, 0);  rot_wire<0 >(vr, vi, xbuf, waveId, lane, M); }
        { CMat M = mk_rot(qp, l, 1);  rot_wire<1 >(vr, vi, xbuf, waveId, lane, M); }
        { CMat M = mk_rot(qp, l, 2);  rot_wire<2 >(vr, vi, xbuf, waveId, lane, M); }
        { CMat M = mk_rot(qp, l, 3);  rot_wire<3 >(vr, vi, xbuf, waveId, lane, M); }
        { CMat M = mk_rot(qp, l, 4);  rot_wire<4 >(vr, vi, xbuf, waveId, lane, M); }
        { CMat M = mk_rot(qp, l, 5);  rot_wire<5 >(vr, vi, xbuf, waveId, lane, M); }
        { CMat M = mk_rot(qp, l, 6);  rot_wire<6 >(vr, vi, xbuf, waveId, lane, M); }
        { CMat M = mk_rot(qp, l, 7);  rot_wire<7 >(vr, vi, xbuf, waveId, lane, M); }
        { CMat M = mk_rot(qp, l, 8);  rot_wire<8 >(vr, vi, xbuf, waveId, lane, M); }
        { CMat M = mk_rot(qp, l, 9);  rot_wire<9 >(vr, vi, xbuf, waveId, lane, M); }
        { CMat M = mk_rot(qp, l, 10); rot_wire<10>(vr, vi, xbuf, waveId, lane, M); }
        { CMat M = mk_rot(qp, l, 11); rot_wire<11>(vr, vi, xbuf, waveId, lane, M); }
        if (l == 0) {                 // r = 1
            int j = lane;
            j ^= (j & 2)  ? 1  : 0;           // C(5,6)
            j ^= (j & 4)  ? 2  : 0;           // C(4,5)
            j ^= (j & 8)  ? 4  : 0;           // C(3,4)
            j ^= (j & 16) ? 8  : 0;           // C(2,3)
            j ^= (j & 32) ? 16 : 0;           // C(1,2)
            j ^= (waveId & 2) ? 32 : 0;       // C(0,1)
            shfl_perm(vr, vi, j);
            cnot<6,7>(vr,vi,xbuf,waveId,lane);   cnot<7,8>(vr,vi,xbuf,waveId,lane);
            cnot<8,9>(vr,vi,xbuf,waveId,lane);   cnot<9,10>(vr,vi,xbuf,waveId,lane);
            cnot<10,11>(vr,vi,xbuf,waveId,lane); cnot<11,0>(vr,vi,xbuf,waveId,lane);
        } else {                      // r = 2
            int j = lane;
            j ^= (j & 4)  ? 1  : 0;           // C(4,6)
            j ^= (j & 8)  ? 2  : 0;           // C(3,5)
            j ^= (j & 16) ? 4  : 0;           // C(2,4)
            j ^= (j & 32) ? 8  : 0;           // C(1,3)
            j ^= (waveId & 2) ? 16 : 0;       // C(0,2)
            shfl_perm(vr, vi, j);
            cnot<5,7>(vr,vi,xbuf,waveId,lane);   cnot<6,8>(vr,vi,xbuf,waveId,lane);
            cnot<7,9>(vr,vi,xbuf,waveId,lane);   cnot<8,10>(vr,vi,xbuf,waveId,lane);
            cnot<9,11>(vr,vi,xbuf,waveId,lane);  cnot<10,0>(vr,vi,xbuf,waveId,lane);
            cnot<11,1>(vr,vi,xbuf,waveId,lane);
        }
    }

    // FRQI-2 Hadamards on wires 1..11
    h_wire<1>(vr,vi,xbuf,waveId,lane);  h_wire<2>(vr,vi,xbuf,waveId,lane);
    h_wire<3>(vr,vi,xbuf,waveId,lane);  h_wire<4>(vr,vi,xbuf,waveId,lane);
    h_wire<5>(vr,vi,xbuf,waveId,lane);  h_wire<6>(vr,vi,xbuf,waveId,lane);
    h_wire<7>(vr,vi,xbuf,waveId,lane);  h_wire<8>(vr,vi,xbuf,waveId,lane);
    h_wire<9>(vr,vi,xbuf,waveId,lane);  h_wire<10>(vr,vi,xbuf,waveId,lane);
    h_wire<11>(vr,vi,xbuf,waveId,lane);

    // stage xf row
    {
        const float4* x4 = (const float4*)(xf + b * 2048);
        ((float4*)ang)[tid]       = x4[tid];
        ((float4*)ang)[tid + 256] = x4[tid + 256];
    }
    __syncthreads();

    // fused UC-RY(img) on wire0 (vm=2) + Z(0) expectation
    exch_put(xbuf, (waveId << 6) + lane, vr, vi);
    {
        const float4* p = (const float4*)xbuf;
        const int ps = ((waveId ^ 2) << 6) + lane;
        const bool hi = waveId & 2;
        float acc = 0.0f;
        #pragma unroll
        for (int j = 0; j < 8; ++j) {
            float4 q = p[(j << 8) + ps];
            #pragma unroll
            for (int h = 0; h < 2; ++h) {
                const int e = 2*j + h;
                const float prr = h ? q.z : q.x;
                const float pii = h ? q.w : q.y;
                int v = (lane << 5) | ((waveId & 1) << 4) | e;
                int rv = (int)(__brev((unsigned)v) >> 21);
                float s, c;
                sincosf(0.5f * ang[rv], &s, &c);
                float nr = hi ? (s*prr + c*vr[e]) : (c*vr[e] - s*prr);
                float ni = hi ? (s*pii + c*vi[e]) : (c*vi[e] - s*pii);
                acc += nr*nr + ni*ni;
            }
        }
        if (!hi) acc = -acc;
        #pragma unroll
        for (int off = 32; off > 0; off >>= 1) acc += __shfl_down(acc, off, 64);
        __syncthreads();
        if (lane == 0) xbuf[waveId] = acc;
        __syncthreads();
        if (tid == 0) out[b] = xbuf[0] + xbuf[1] + xbuf[2] + xbuf[3];
    }
}

extern "C" void kernel_launch(void* const* d_in, const int* in_sizes, int n_in,
                              void* d_out, int out_size, void* d_ws, size_t ws_size,
                              hipStream_t stream) {
    const float* x    = (const float*)d_in[0];   // (1024,2048)
    const float* W    = (const float*)d_in[1];   // (512,2048)
    const float* bias = (const float*)d_in[2];   // (512,)
    const float* qp   = (const float*)d_in[3];   // (2,12,3)
    float* out = (float*)d_out;                  // (1024,)

    const size_t MB = 1024ull * 1024;
    const size_t BASE = 12 * MB;                 // xc 8MB + wc 4MB
    if (ws_size >= BASE + 4 * MB) {
        unsigned short* xc = (unsigned short*)d_ws;
        unsigned short* wc = (unsigned short*)((char*)d_ws + 8 * MB);
        float* P = (float*)((char*)d_ws + BASE);
        split_all<<<3072, 256, 0, stream>>>(x, W, xc, wc);
        if (ws_size >= BASE + 16 * MB) {
            // SK=8, 32x64 wave tiles: (1024/32)*8/4 = 64 blocks per z
            gemm_tile<2, 16><<<64 * 8, 256, 0, stream>>>(xc, wc, P);
            reduce_kernel<<<2048, 256, 0, stream>>>(P, bias, 8);
        } else if (ws_size >= BASE + 8 * MB) {
            // SK=4
            gemm_tile<2, 32><<<64 * 4, 256, 0, stream>>>(xc, wc, P);
            reduce_kernel<<<2048, 256, 0, stream>>>(P, bias, 4);
        } else {
            // SK=2, 16x64 wave tiles: (1024/16)*8/4 = 128 blocks per z
            gemm_tile<1, 64><<<128 * 2, 256, 0, stream>>>(xc, wc, P);
            reduce_kernel<<<2048, 256, 0, stream>>>(P, bias, 2);
        }
        circuit_kernel<<<1024, 256, 0, stream>>>(P, x, qp, out);
    } else {
        // fallback: fp32 split-K partials + reduce
        float* P = (float*)d_ws;
        const size_t slab = 1024 * 512 * sizeof(float);
        int SK = 1;
        if      (ws_size >= 16 * slab) SK = 16;
        else if (ws_size >=  8 * slab) SK = 8;
        else if (ws_size >=  4 * slab) SK = 4;
        else if (ws_size >=  2 * slab) SK = 2;
        dim3 ggrid(8, 4, SK);
        gemm_f32<<<ggrid, 256, 0, stream>>>(x, W, P);
        reduce_kernel<<<2048, 256, 0, stream>>>(P, bias, SK);
        circuit_kernel<<<1024, 256, 0, stream>>>(P, x, qp, out);
    }
}

// Round 10
// 150.510 us; speedup vs baseline: 1.0983x; 1.0983x over previous
//
#include <hip/hip_runtime.h>
#include <math.h>

#define RS2f 0.70710678118654752f

typedef __attribute__((ext_vector_type(8))) short bf16x8;
typedef __attribute__((ext_vector_type(4))) float f32x4;

__device__ __forceinline__ unsigned short f2bf(float f) {
    unsigned u = __float_as_uint(f);
    unsigned r = (u + 0x7fffu + ((u >> 16) & 1u)) >> 16;   // RNE
    return (unsigned short)r;
}
__device__ __forceinline__ float bf2f(unsigned short h) {
    return __uint_as_float(((unsigned)h) << 16);
}

// ==================================================================
// Fused convert: x (1024x2048) and W (512x2048) fp32 -> bf16 hi/lo
// concat along K (row stride 4096 = [hi | lo]).
// ==================================================================
__global__ __launch_bounds__(256) void split_all(const float* __restrict__ x,
                                                 const float* __restrict__ W,
                                                 unsigned short* __restrict__ xc,
                                                 unsigned short* __restrict__ wc) {
    int idx = blockIdx.x * 256 + threadIdx.x;      // 786432 total
    const float* src; unsigned short* dst;
    if (idx < 524288) { src = x; dst = xc; }
    else              { idx -= 524288; src = W; dst = wc; }
    int m = idx >> 9;
    int c4 = (idx & 511) << 2;
    const float4 v = *(const float4*)&src[m * 2048 + c4];
    ushort4 hi, lo;
    hi.x = f2bf(v.x); lo.x = f2bf(v.x - bf2f(hi.x));
    hi.y = f2bf(v.y); lo.y = f2bf(v.y - bf2f(hi.y));
    hi.z = f2bf(v.z); lo.z = f2bf(v.z - bf2f(hi.z));
    hi.w = f2bf(v.w); lo.w = f2bf(v.w - bf2f(hi.w));
    *(ushort4*)&dst[m * 4096 + c4] = hi;
    *(ushort4*)&dst[m * 4096 + 2048 + c4] = lo;
}

// ==================================================================
// MFMA GEMM partials. 64x64 tile, BK=64, 4 waves (wave wv = rows
// wv*16..+15, all 64 cols). Coalesced staging (8 lanes = 128 B
// contiguous -- R9's direct-fragment loads were 64-line scattered and
// ran at ~4 B/cyc/CU), padded LDS (stride 72 shorts -> 2-way banks,
// free), register prefetch. Grid (16,8,SK): SK=8 -> 1024 blocks =
// 4 blocks/CU = 16 waves/CU. Tile traffic 134 MB (vs R8's 192).
// ==================================================================
__global__ __launch_bounds__(256) void gemm64(const unsigned short* __restrict__ A,  // 1024x4096
                                              const unsigned short* __restrict__ B,  // 512x4096
                                              float* __restrict__ P, int nch) {
    __shared__ short As[64 * 72];
    __shared__ short Bs[64 * 72];
    const int tid = threadIdx.x, lane = tid & 63, wv = tid >> 6;
    const int quad = lane >> 4, mrow = lane & 15;
    const int m0 = blockIdx.x * 64, n0 = blockIdx.y * 64;
    const int kb = blockIdx.z * nch * 64;
    const int srow = tid >> 2;            // 0..63
    const int sk = (tid & 3) * 16;        // 0,16,32,48
    const unsigned short* Arow = A + (size_t)(m0 + srow) * 4096 + kb + sk;
    const unsigned short* Brow = B + (size_t)(n0 + srow) * 4096 + kb + sk;

    f32x4 acc[4];
    #pragma unroll
    for (int j = 0; j < 4; ++j) acc[j] = (f32x4){0.f, 0.f, 0.f, 0.f};

    float4 a0 = *(const float4*)Arow;
    float4 a1 = *(const float4*)(Arow + 8);
    float4 b0 = *(const float4*)Brow;
    float4 b1 = *(const float4*)(Brow + 8);

    for (int ch = 0; ch < nch; ++ch) {
        __syncthreads();
        *(float4*)&As[srow * 72 + sk]     = a0;
        *(float4*)&As[srow * 72 + sk + 8] = a1;
        *(float4*)&Bs[srow * 72 + sk]     = b0;
        *(float4*)&Bs[srow * 72 + sk + 8] = b1;
        __syncthreads();
        if (ch + 1 < nch) {
            const int o = (ch + 1) * 64;
            a0 = *(const float4*)(Arow + o);
            a1 = *(const float4*)(Arow + o + 8);
            b0 = *(const float4*)(Brow + o);
            b1 = *(const float4*)(Brow + o + 8);
        }
        #pragma unroll
        for (int ks = 0; ks < 2; ++ks) {
            bf16x8 af = *(const bf16x8*)&As[(wv * 16 + mrow) * 72 + ks * 32 + quad * 8];
            #pragma unroll
            for (int j = 0; j < 4; ++j) {
                bf16x8 bf = *(const bf16x8*)&Bs[(j * 16 + mrow) * 72 + ks * 32 + quad * 8];
                acc[j] = __builtin_amdgcn_mfma_f32_16x16x32_bf16(af, bf, acc[j], 0, 0, 0);
            }
        }
    }
    // C/D layout: col = lane&15, row = quad*4 + r
    float* Pz = P + (size_t)blockIdx.z * 524288;
    #pragma unroll
    for (int j = 0; j < 4; ++j)
        #pragma unroll
        for (int r = 0; r < 4; ++r)
            Pz[(m0 + wv * 16 + quad * 4 + r) * 512 + n0 + j * 16 + mrow] = acc[j][r];
}

// ==================================================================
// Fallback fp32 GEMM (only if ws too small for bf16 buffers)
// ==================================================================
__global__ __launch_bounds__(256) void gemm_f32(const float* __restrict__ A,
                                                const float* __restrict__ W,
                                                float* __restrict__ P) {
    __shared__ float Asf[32][128];
    __shared__ float Bsf[32][128];
    const int tid = threadIdx.x;
    const int m0 = blockIdx.x * 128;
    const int n0 = blockIdx.y * 128;
    const int kchunk = 2048 / gridDim.z;
    const int kbase = blockIdx.z * kchunk;
    const int tm = tid >> 4, tn = tid & 15;
    const int srow = tid >> 1;
    const int scol = (tid & 1) * 16;
    float acc[8][8] = {};
    for (int k0 = kbase; k0 < kbase + kchunk; k0 += 32) {
        float4 a[4], w[4];
        const float4* Ap = (const float4*)&A[(m0 + srow) * 2048 + k0 + scol];
        const float4* Wp = (const float4*)&W[(n0 + srow) * 2048 + k0 + scol];
        #pragma unroll
        for (int q = 0; q < 4; ++q) { a[q] = Ap[q]; w[q] = Wp[q]; }
        __syncthreads();
        #pragma unroll
        for (int q = 0; q < 4; ++q) {
            Asf[scol + 4*q + 0][srow] = a[q].x; Asf[scol + 4*q + 1][srow] = a[q].y;
            Asf[scol + 4*q + 2][srow] = a[q].z; Asf[scol + 4*q + 3][srow] = a[q].w;
            Bsf[scol + 4*q + 0][srow] = w[q].x; Bsf[scol + 4*q + 1][srow] = w[q].y;
            Bsf[scol + 4*q + 2][srow] = w[q].z; Bsf[scol + 4*q + 3][srow] = w[q].w;
        }
        __syncthreads();
        #pragma unroll
        for (int kk = 0; kk < 32; ++kk) {
            float4 af0 = *(const float4*)&Asf[kk][tm * 8];
            float4 af1 = *(const float4*)&Asf[kk][tm * 8 + 4];
            float4 bf0 = *(const float4*)&Bsf[kk][tn * 8];
            float4 bf1 = *(const float4*)&Bsf[kk][tn * 8 + 4];
            float av[8] = {af0.x,af0.y,af0.z,af0.w,af1.x,af1.y,af1.z,af1.w};
            float bv[8] = {bf0.x,bf0.y,bf0.z,bf0.w,bf1.x,bf1.y,bf1.z,bf1.w};
            #pragma unroll
            for (int r = 0; r < 8; ++r)
                #pragma unroll
                for (int c = 0; c < 8; ++c)
                    acc[r][c] += av[r] * bv[c];
        }
    }
    float* Pz = P + (size_t)blockIdx.z * 524288;
    #pragma unroll
    for (int r = 0; r < 8; ++r) {
        float4 lo = make_float4(acc[r][0], acc[r][1], acc[r][2], acc[r][3]);
        float4 hi = make_float4(acc[r][4], acc[r][5], acc[r][6], acc[r][7]);
        float* dst = &Pz[(m0 + tm*8 + r) * 512 + n0 + tn*8];
        *(float4*)dst = lo;
        *(float4*)(dst + 4) = hi;
    }
}

// ==================================================================
// Kernel 3: 12-qubit circuit — EXACT R5/R8 gate structure (77 us
// measured; half-pass and cmt-hoist variants both regressed -- do not
// touch). ONLY change vs R8: the com-row staging now sums the SK
// partial slabs + bias directly (reduce kernel fused away).
//   idx = (w1<<11) | (lane<<5) | (w0<<4) | e,  waveId = (w1<<1)|w0
//   V-wires: wire0 -> vm=2, wire7 -> vm=1
//   L-wires: wires1..6 -> lane bits 5..0
//   E-wires: wires8..11 -> e bits 3..0
// ==================================================================
struct CMat { float m00r,m00i,m01r,m01i,m10r,m10i,m11r,m11i; };

__device__ __forceinline__ CMat mk_rot(const float* __restrict__ qp, int l, int w) {
    const float* g = qp + (l * 12 + w) * 3;
    float phi = g[0], th = g[1], om = g[2];
    float st, ct, sa, ca, sb, cb;
    sincosf(0.5f * th, &st, &ct);
    sincosf(0.5f * (phi + om), &sa, &ca);
    sincosf(0.5f * (phi - om), &sb, &cb);
    CMat M;
    M.m00r =  ct * ca; M.m00i = -ct * sa;
    M.m01r = -st * cb; M.m01i = -st * sb;
    M.m10r =  st * cb; M.m10i = -st * sb;
    M.m11r =  ct * ca; M.m11i =  ct * sa;
    return M;
}

template<int W> struct WI {
    static constexpr int kind = (W == 0 || W == 7) ? 2 : ((W >= 1 && W <= 6) ? 1 : 0);
    static constexpr int eb   = (W >= 8) ? (11 - W) : 0;
    static constexpr int lm   = (W >= 1 && W <= 6) ? (1 << (6 - W)) : 0;
    static constexpr int vm   = (W == 0) ? 2 : ((W == 7) ? 1 : 0);
};

__device__ __forceinline__ void exch_put(float* xbuf, int slot,
                                         const float vr[16], const float vi[16]) {
    __syncthreads();
    float4* p = (float4*)xbuf;
    #pragma unroll
    for (int j = 0; j < 8; ++j)
        p[(j << 8) + slot] = make_float4(vr[2*j], vi[2*j], vr[2*j+1], vi[2*j+1]);
    __syncthreads();
}

__device__ __forceinline__ void shfl_perm(float vr[16], float vi[16], int src) {
    #pragma unroll
    for (int e = 0; e < 16; ++e) {
        vr[e] = __shfl(vr[e], src, 64);
        vi[e] = __shfl(vi[e], src, 64);
    }
}

template<int EB>
__device__ __forceinline__ void rot_local(float vr[16], float vi[16], const CMat& M) {
    #pragma unroll
    for (int e = 0; e < 16; ++e) if (!(e & (1 << EB))) {
        const int e1 = e | (1 << EB);
        float x0r = vr[e],  x0i = vi[e];
        float x1r = vr[e1], x1i = vi[e1];
        vr[e]  = M.m00r*x0r - M.m00i*x0i + M.m01r*x1r - M.m01i*x1i;
        vi[e]  = M.m00r*x0i + M.m00i*x0r + M.m01r*x1i + M.m01i*x1r;
        vr[e1] = M.m10r*x0r - M.m10i*x0i + M.m11r*x1r - M.m11i*x1i;
        vi[e1] = M.m10r*x0i + M.m10i*x0r + M.m11r*x1i + M.m11i*x1r;
    }
}

template<int LM>
__device__ __forceinline__ void rot_lane(float vr[16], float vi[16], int lane, const CMat& M) {
    const bool hi = lane & LM;
    const float Ar = hi ? M.m11r : M.m00r, Ai = hi ? M.m11i : M.m00i;
    const float Br = hi ? M.m10r : M.m01r, Bi = hi ? M.m10i : M.m01i;
    #pragma unroll
    for (int e = 0; e < 16; ++e) {
        float pr = __shfl_xor(vr[e], LM, 64);
        float pi = __shfl_xor(vi[e], LM, 64);
        float orr = vr[e], oi = vi[e];
        vr[e] = Ar*orr - Ai*oi + Br*pr - Bi*pi;
        vi[e] = Ar*oi + Ai*orr + Br*pi + Bi*pr;
    }
}

template<int VM>
__device__ __forceinline__ void rot_wave(float vr[16], float vi[16], float* xbuf,
                                         int waveId, int lane, const CMat& M) {
    exch_put(xbuf, (waveId << 6) + lane, vr, vi);
    const float4* p = (const float4*)xbuf;
    const int ps = ((waveId ^ VM) << 6) + lane;
    const bool hi = waveId & VM;
    const float Ar = hi ? M.m11r : M.m00r, Ai = hi ? M.m11i : M.m00i;
    const float Br = hi ? M.m10r : M.m01r, Bi = hi ? M.m10i : M.m01i;
    #pragma unroll
    for (int j = 0; j < 8; ++j) {
        float4 q = p[(j << 8) + ps];
        const int e0 = 2*j, e1 = 2*j + 1;
        float r0 = vr[e0], i0 = vi[e0], r1 = vr[e1], i1 = vi[e1];
        vr[e0] = Ar*r0 - Ai*i0 + Br*q.x - Bi*q.y;
        vi[e0] = Ar*i0 + Ai*r0 + Br*q.y + Bi*q.x;
        vr[e1] = Ar*r1 - Ai*i1 + Br*q.z - Bi*q.w;
        vi[e1] = Ar*i1 + Ai*r1 + Br*q.w + Bi*q.z;
    }
}

template<int W>
__device__ __forceinline__ void rot_wire(float vr[16], float vi[16], float* xbuf,
                                         int waveId, int lane, const CMat& M) {
    if constexpr (WI<W>::kind == 0)      rot_local<WI<W>::eb>(vr, vi, M);
    else if constexpr (WI<W>::kind == 1) rot_lane<WI<W>::lm>(vr, vi, lane, M);
    else                                 rot_wave<WI<W>::vm>(vr, vi, xbuf, waveId, lane, M);
}

template<int C, int T>
__device__ __forceinline__ void cnot(float vr[16], float vi[16], float* xbuf,
                                     int waveId, int lane) {
    constexpr int ck = WI<C>::kind, tk = WI<T>::kind;
    if constexpr (ck == 0 && tk == 0) {
        constexpr int cb = 1 << WI<C>::eb, tb = 1 << WI<T>::eb;
        #pragma unroll
        for (int e = 0; e < 16; ++e) if ((e & cb) && !(e & tb)) {
            const int e1 = e | tb;
            float t = vr[e]; vr[e] = vr[e1]; vr[e1] = t;
            t = vi[e]; vi[e] = vi[e1]; vi[e1] = t;
        }
    } else if constexpr (ck == 0 && tk == 1) {
        constexpr int cb = 1 << WI<C>::eb, tm = WI<T>::lm;
        #pragma unroll
        for (int e = 0; e < 16; ++e) if (e & cb) {
            vr[e] = __shfl_xor(vr[e], tm, 64);
            vi[e] = __shfl_xor(vi[e], tm, 64);
        }
    } else if constexpr (ck == 0 && tk == 2) {
        constexpr int cb = 1 << WI<C>::eb, vm = WI<T>::vm;
        exch_put(xbuf, (waveId << 6) + lane, vr, vi);
        const float4* p = (const float4*)xbuf;
        const int ps = ((waveId ^ vm) << 6) + lane;
        #pragma unroll
        for (int j = 0; j < 8; ++j) {
            if ((((2*j) & cb) != 0) || (((2*j+1) & cb) != 0)) {
                float4 q = p[(j << 8) + ps];
                if (((2*j) & cb) != 0)   { vr[2*j]   = q.x; vi[2*j]   = q.y; }
                if (((2*j+1) & cb) != 0) { vr[2*j+1] = q.z; vi[2*j+1] = q.w; }
            }
        }
    } else if constexpr (ck == 1 && tk == 0) {
        constexpr int cm = WI<C>::lm, tb = 1 << WI<T>::eb;
        const bool cc = lane & cm;
        #pragma unroll
        for (int e = 0; e < 16; ++e) if (!(e & tb)) {
            const int e1 = e | tb;
            float a = vr[e], bb = vr[e1];
            vr[e] = cc ? bb : a; vr[e1] = cc ? a : bb;
            a = vi[e]; bb = vi[e1];
            vi[e] = cc ? bb : a; vi[e1] = cc ? a : bb;
        }
    } else if constexpr (ck == 1 && tk == 1) {
        constexpr int cm = WI<C>::lm, tm = WI<T>::lm;
        const int src = (lane & cm) ? (lane ^ tm) : lane;
        shfl_perm(vr, vi, src);
    } else if constexpr (ck == 1 && tk == 2) {
        constexpr int cm = WI<C>::lm, vm = WI<T>::vm;
        exch_put(xbuf, (waveId << 6) + lane, vr, vi);
        const float4* p = (const float4*)xbuf;
        const int ps = ((waveId ^ vm) << 6) + lane;
        const bool take = lane & cm;
        #pragma unroll
        for (int j = 0; j < 8; ++j) {
            float4 q = p[(j << 8) + ps];
            vr[2*j]   = take ? q.x : vr[2*j];   vi[2*j]   = take ? q.y : vi[2*j];
            vr[2*j+1] = take ? q.z : vr[2*j+1]; vi[2*j+1] = take ? q.w : vi[2*j+1];
        }
    } else if constexpr (ck == 2 && tk == 0) {
        constexpr int vm = WI<C>::vm, tb = 1 << WI<T>::eb;
        if (waveId & vm) {
            #pragma unroll
            for (int e = 0; e < 16; ++e) if (!(e & tb)) {
                const int e1 = e | tb;
                float t = vr[e]; vr[e] = vr[e1]; vr[e1] = t;
                t = vi[e]; vi[e] = vi[e1]; vi[e1] = t;
            }
        }
    } else {
        constexpr int vm = WI<C>::vm, tm = WI<T>::lm;
        if (waveId & vm) {
            #pragma unroll
            for (int e = 0; e < 16; ++e) {
                vr[e] = __shfl_xor(vr[e], tm, 64);
                vi[e] = __shfl_xor(vi[e], tm, 64);
            }
        }
    }
}

template<int W>
__device__ __forceinline__ void h_wire(float vr[16], float vi[16], float* xbuf,
                                       int waveId, int lane) {
    if constexpr (WI<W>::kind == 0) {
        constexpr int tb = 1 << WI<W>::eb;
        #pragma unroll
        for (int e = 0; e < 16; ++e) if (!(e & tb)) {
            const int e1 = e | tb;
            float x0 = vr[e], x1 = vr[e1];
            vr[e] = (x0 + x1) * RS2f; vr[e1] = (x0 - x1) * RS2f;
            x0 = vi[e]; x1 = vi[e1];
            vi[e] = (x0 + x1) * RS2f; vi[e1] = (x0 - x1) * RS2f;
        }
    } else if constexpr (WI<W>::kind == 1) {
        constexpr int m = WI<W>::lm;
        const float sgn = (lane & m) ? -RS2f : RS2f;
        #pragma unroll
        for (int e = 0; e < 16; ++e) {
            float pr = __shfl_xor(vr[e], m, 64);
            float pi = __shfl_xor(vi[e], m, 64);
            vr[e] = pr * RS2f + vr[e] * sgn;
            vi[e] = pi * RS2f + vi[e] * sgn;
        }
    } else {
        constexpr int vm = WI<W>::vm;
        exch_put(xbuf, (waveId << 6) + lane, vr, vi);
        const float4* p = (const float4*)xbuf;
        const int ps = ((waveId ^ vm) << 6) + lane;
        const float sgn = (waveId & vm) ? -RS2f : RS2f;
        #pragma unroll
        for (int j = 0; j < 8; ++j) {
            float4 q = p[(j << 8) + ps];
            vr[2*j]   = q.x * RS2f + vr[2*j]   * sgn;
            vi[2*j]   = q.y * RS2f + vi[2*j]   * sgn;
            vr[2*j+1] = q.z * RS2f + vr[2*j+1] * sgn;
            vi[2*j+1] = q.w * RS2f + vi[2*j+1] * sgn;
        }
    }
}

__global__ __launch_bounds__(256) void circuit_kernel(const float* __restrict__ P,    // SK slabs
                                                      const float* __restrict__ bias, // (512,)
                                                      const float* __restrict__ xf,   // (1024,2048)
                                                      const float* __restrict__ qp,
                                                      float* __restrict__ out, int SK) {
    __shared__ float xbuf[8192];         // 32 KB exchange buffer
    __shared__ float ang[2048];          // 8 KB: com row, later xf row
    const int tid = threadIdx.x;
    const int lane = tid & 63;
    const int waveId = tid >> 6;
    const int b = blockIdx.x;

    // fused reduce: com row = bias + sum of SK partial slabs
    if (tid < 128) {
        float4 s = ((const float4*)bias)[tid];
        for (int z = 0; z < SK; ++z) {
            float4 p4 = *(const float4*)&P[(size_t)z * 524288 + b * 512 + tid * 4];
            s.x += p4.x; s.y += p4.y; s.z += p4.z; s.w += p4.w;
        }
        ((float4*)ang)[tid] = s;
    }
    __syncthreads();

    float vr[16], vi[16];
    #pragma unroll
    for (int e = 0; e < 16; ++e) { vr[e] = 0.0f; vi[e] = 0.0f; }

    // FRQI-1 closed form: amp nonzero where wires10,11 = 0 -> e in {0,4,8,12}
    const float K9 = 0.044194173824159216f;   // 2^-4.5
    #pragma unroll
    for (int m = 0; m < 4; ++m) {
        int j = (lane << 3) | ((waveId & 1) << 2) | m;
        int rj = (int)(__brev((unsigned)j) >> 23);
        float s, c;
        sincosf(0.5f * ang[rj], &s, &c);
        vr[m << 2] = K9 * ((waveId & 2) ? s : c);
    }

    #pragma unroll 1
    for (int l = 0; l < 2; ++l) {
        { CMat M = mk_rot(qp, l, 0);  rot_wire<0 >(vr, vi, xbuf, waveId, lane, M); }
        { CMat M = mk_rot(qp, l, 1);  rot_wire<1 >(vr, vi, xbuf, waveId, lane, M); }
        { CMat M = mk_rot(qp, l, 2);  rot_wire<2 >(vr, vi, xbuf, waveId, lane, M); }
        { CMat M = mk_rot(qp, l, 3);  rot_wire<3 >(vr, vi, xbuf, waveId, lane, M); }
        { CMat M = mk_rot(qp, l, 4);  rot_wire<4 >(vr, vi, xbuf, waveId, lane, M); }
        { CMat M = mk_rot(qp, l, 5);  rot_wire<5 >(vr, vi, xbuf, waveId, lane, M); }
        { CMat M = mk_rot(qp, l, 6);  rot_wire<6 >(vr, vi, xbuf, waveId, lane, M); }
        { CMat M = mk_rot(qp, l, 7);  rot_wire<7 >(vr, vi, xbuf, waveId, lane, M); }
        { CMat M = mk_rot(qp, l, 8);  rot_wire<8 >(vr, vi, xbuf, waveId, lane, M); }
        { CMat M = mk_rot(qp, l, 9);  rot_wire<9 >(vr, vi, xbuf, waveId, lane, M); }
        { CMat M = mk_rot(qp, l, 10); rot_wire<10>(vr, vi, xbuf, waveId, lane, M); }
        { CMat M = mk_rot(qp, l, 11); rot_wire<11>(vr, vi, xbuf, waveId, lane, M); }
        if (l == 0) {                 // r = 1
            int j = lane;
            j ^= (j & 2)  ? 1  : 0;           // C(5,6)
            j ^= (j & 4)  ? 2  : 0;           // C(4,5)
            j ^= (j & 8)  ? 4  : 0;           // C(3,4)
            j ^= (j & 16) ? 8  : 0;           // C(2,3)
            j ^= (j & 32) ? 16 : 0;           // C(1,2)
            j ^= (waveId & 2) ? 32 : 0;       // C(0,1)
            shfl_perm(vr, vi, j);
            cnot<6,7>(vr,vi,xbuf,waveId,lane);   cnot<7,8>(vr,vi,xbuf,waveId,lane);
            cnot<8,9>(vr,vi,xbuf,waveId,lane);   cnot<9,10>(vr,vi,xbuf,waveId,lane);
            cnot<10,11>(vr,vi,xbuf,waveId,lane); cnot<11,0>(vr,vi,xbuf,waveId,lane);
        } else {                      // r = 2
            int j = lane;
            j ^= (j & 4)  ? 1  : 0;           // C(4,6)
            j ^= (j & 8)  ? 2  : 0;           // C(3,5)
            j ^= (j & 16) ? 4  : 0;           // C(2,4)
            j ^= (j & 32) ? 8  : 0;           // C(1,3)
            j ^= (waveId & 2) ? 16 : 0;       // C(0,2)
            shfl_perm(vr, vi, j);
            cnot<5,7>(vr,vi,xbuf,waveId,lane);   cnot<6,8>(vr,vi,xbuf,waveId,lane);
            cnot<7,9>(vr,vi,xbuf,waveId,lane);   cnot<8,10>(vr,vi,xbuf,waveId,lane);
            cnot<9,11>(vr,vi,xbuf,waveId,lane);  cnot<10,0>(vr,vi,xbuf,waveId,lane);
            cnot<11,1>(vr,vi,xbuf,waveId,lane);
        }
    }

    // FRQI-2 Hadamards on wires 1..11
    h_wire<1>(vr,vi,xbuf,waveId,lane);  h_wire<2>(vr,vi,xbuf,waveId,lane);
    h_wire<3>(vr,vi,xbuf,waveId,lane);  h_wire<4>(vr,vi,xbuf,waveId,lane);
    h_wire<5>(vr,vi,xbuf,waveId,lane);  h_wire<6>(vr,vi,xbuf,waveId,lane);
    h_wire<7>(vr,vi,xbuf,waveId,lane);  h_wire<8>(vr,vi,xbuf,waveId,lane);
    h_wire<9>(vr,vi,xbuf,waveId,lane);  h_wire<10>(vr,vi,xbuf,waveId,lane);
    h_wire<11>(vr,vi,xbuf,waveId,lane);

    // stage xf row
    {
        const float4* x4 = (const float4*)(xf + b * 2048);
        ((float4*)ang)[tid]       = x4[tid];
        ((float4*)ang)[tid + 256] = x4[tid + 256];
    }
    __syncthreads();

    // fused UC-RY(img) on wire0 (vm=2) + Z(0) expectation
    exch_put(xbuf, (waveId << 6) + lane, vr, vi);
    {
        const float4* p = (const float4*)xbuf;
        const int ps = ((waveId ^ 2) << 6) + lane;
        const bool hi = waveId & 2;
        float acc = 0.0f;
        #pragma unroll
        for (int j = 0; j < 8; ++j) {
            float4 q = p[(j << 8) + ps];
            #pragma unroll
            for (int h = 0; h < 2; ++h) {
                const int e = 2*j + h;
                const float prr = h ? q.z : q.x;
                const float pii = h ? q.w : q.y;
                int v = (lane << 5) | ((waveId & 1) << 4) | e;
                int rv = (int)(__brev((unsigned)v) >> 21);
                float s, c;
                sincosf(0.5f * ang[rv], &s, &c);
                float nr = hi ? (s*prr + c*vr[e]) : (c*vr[e] - s*prr);
                float ni = hi ? (s*pii + c*vi[e]) : (c*vi[e] - s*pii);
                acc += nr*nr + ni*ni;
            }
        }
        if (!hi) acc = -acc;
        #pragma unroll
        for (int off = 32; off > 0; off >>= 1) acc += __shfl_down(acc, off, 64);
        __syncthreads();
        if (lane == 0) xbuf[waveId] = acc;
        __syncthreads();
        if (tid == 0) out[b] = xbuf[0] + xbuf[1] + xbuf[2] + xbuf[3];
    }
}

extern "C" void kernel_launch(void* const* d_in, const int* in_sizes, int n_in,
                              void* d_out, int out_size, void* d_ws, size_t ws_size,
                              hipStream_t stream) {
    const float* x    = (const float*)d_in[0];   // (1024,2048)
    const float* W    = (const float*)d_in[1];   // (512,2048)
    const float* bias = (const float*)d_in[2];   // (512,)
    const float* qp   = (const float*)d_in[3];   // (2,12,3)
    float* out = (float*)d_out;                  // (1024,)

    const size_t MB = 1024ull * 1024;
    const size_t BASE = 12 * MB;                 // xc 8MB + wc 4MB
    if (ws_size >= BASE + 4 * MB) {
        unsigned short* xc = (unsigned short*)d_ws;
        unsigned short* wc = (unsigned short*)((char*)d_ws + 8 * MB);
        float* P = (float*)((char*)d_ws + BASE);
        int SK;
        if      (ws_size >= BASE + 16 * MB) SK = 8;
        else if (ws_size >= BASE + 8 * MB)  SK = 4;
        else                                SK = 2;
        split_all<<<3072, 256, 0, stream>>>(x, W, xc, wc);
        dim3 g(16, 8, SK);                       // 64x64 tiles, split-K
        gemm64<<<g, 256, 0, stream>>>(xc, wc, P, 4096 / SK / 64);
        circuit_kernel<<<1024, 256, 0, stream>>>(P, bias, x, qp, out, SK);
    } else {
        // fallback: fp32 split-K partials, reduce fused into circuit
        float* P = (float*)d_ws;
        const size_t slab = 1024 * 512 * sizeof(float);
        int SK = 1;
        if      (ws_size >= 16 * slab) SK = 16;
        else if (ws_size >=  8 * slab) SK = 8;
        else if (ws_size >=  4 * slab) SK = 4;
        else if (ws_size >=  2 * slab) SK = 2;
        dim3 ggrid(8, 4, SK);
        gemm_f32<<<ggrid, 256, 0, stream>>>(x, W, P);
        circuit_kernel<<<1024, 256, 0, stream>>>(P, bias, x, qp, out, SK);
    }
}